// Round 4
// baseline (817.688 us; speedup 1.0000x reference)
//
#include <hip/hip_runtime.h>

#define IN_F 128
#define OUT_F 64

// ---------------------------------------------------------------------------
// Kernel 1: sp = x @ W    x:[N,128] f32, W:[128,64] f32 -> sp:[N,64] f32
// Block = 256 threads = 16 rows x 16 threads/row; each thread computes 4
// output features. W (32 KB) in LDS row-major [k][j]; x rows staged in LDS
// with padded stride 132 so the 4 distinct per-wave row addresses hit
// distinct banks.
// ---------------------------------------------------------------------------
__global__ __launch_bounds__(256, 2) void gemm_xw(
    const float* __restrict__ x, const float* __restrict__ W,
    float* __restrict__ sp, int n_nodes)
{
    __shared__ float Wlds[IN_F * OUT_F];   // 32 KB, [k][j]
    __shared__ float xlds[16][IN_F + 4];   // stride 132 floats (pad)

    const int t = threadIdx.x;

    // Cooperative load of W: 8192 floats / 256 threads = 8 float4 each.
    for (int i = t * 4; i < IN_F * OUT_F; i += 256 * 4) {
        *(float4*)&Wlds[i] = *(const float4*)&W[i];
    }

    const int row0 = blockIdx.x * 16;

    // Stage 16 rows of x (2048 floats): each thread loads 8 consecutive floats.
    {
        const int base = t * 8;
        const int r = base >> 7;     // /128
        const int k = base & 127;
        if (row0 + r < n_nodes) {
            float4 a = *(const float4*)&x[(size_t)(row0 + r) * IN_F + k];
            float4 b = *(const float4*)&x[(size_t)(row0 + r) * IN_F + k + 4];
            *(float4*)&xlds[r][k]     = a;
            *(float4*)&xlds[r][k + 4] = b;
        }
    }
    __syncthreads();

    const int rowInBlk = t >> 4;          // 0..15
    const int fGroup   = (t & 15) * 4;    // 0,4,...,60
    const int row = row0 + rowInBlk;
    if (row >= n_nodes) return;

    float accx = 0.f, accy = 0.f, accz = 0.f, accw = 0.f;
    #pragma unroll
    for (int k = 0; k < IN_F; k += 4) {
        float4 xv = *(const float4*)&xlds[rowInBlk][k];
        float4 w0 = *(const float4*)&Wlds[(k + 0) * OUT_F + fGroup];
        float4 w1 = *(const float4*)&Wlds[(k + 1) * OUT_F + fGroup];
        float4 w2 = *(const float4*)&Wlds[(k + 2) * OUT_F + fGroup];
        float4 w3 = *(const float4*)&Wlds[(k + 3) * OUT_F + fGroup];
        accx += xv.x * w0.x + xv.y * w1.x + xv.z * w2.x + xv.w * w3.x;
        accy += xv.x * w0.y + xv.y * w1.y + xv.z * w2.y + xv.w * w3.y;
        accz += xv.x * w0.z + xv.y * w1.z + xv.z * w2.z + xv.w * w3.z;
        accw += xv.x * w0.w + xv.y * w1.w + xv.z * w2.w + xv.w * w3.w;
    }
    float4 acc = {accx, accy, accz, accw};
    *(float4*)&sp[(size_t)row * OUT_F + fGroup] = acc;
}

// ---------------------------------------------------------------------------
// Kernel 2: out[n][j] = bias[j]   (d_out is poisoned 0xAA before every call)
// One float4 per thread.
// ---------------------------------------------------------------------------
__global__ __launch_bounds__(256) void init_bias(
    float* __restrict__ out, const float* __restrict__ bias, int n_nodes)
{
    const int t = blockIdx.x * blockDim.x + threadIdx.x;   // float4 index
    const int total = n_nodes * (OUT_F / 4);
    if (t >= total) return;
    const int j = (t & 15) * 4;                            // feature offset
    float4 b = *(const float4*)&bias[j];
    *(float4*)&out[(size_t)t * 4] = b;
}

// ---------------------------------------------------------------------------
// Kernel 3: for each edge (r,c,v): out[r][:] += v * sp[c][:]
// 16 threads per edge, each thread handles 4 features (float4 gather + 4 HW
// f32 atomic adds). unsafeAtomicAdd -> global_atomic_add_f32 (no CAS loop).
// ---------------------------------------------------------------------------
__global__ __launch_bounds__(256) void scatter_edges(
    const int* __restrict__ rows, const int* __restrict__ cols,
    const float* __restrict__ vals, const float* __restrict__ sp,
    float* __restrict__ out, int n_edges)
{
    const int t = blockIdx.x * blockDim.x + threadIdx.x;
    const int e = t >> 4;
    if (e >= n_edges) return;
    const int sub = (t & 15) * 4;

    const int r = rows[e];
    const int c = cols[e];
    const float v = vals[e];

    float4 s = *(const float4*)&sp[(size_t)c * OUT_F + sub];
    float* o = &out[(size_t)r * OUT_F + sub];
    unsafeAtomicAdd(o + 0, v * s.x);
    unsafeAtomicAdd(o + 1, v * s.y);
    unsafeAtomicAdd(o + 2, v * s.z);
    unsafeAtomicAdd(o + 3, v * s.w);
}

// ---------------------------------------------------------------------------
extern "C" void kernel_launch(void* const* d_in, const int* in_sizes, int n_in,
                              void* d_out, int out_size, void* d_ws, size_t ws_size,
                              hipStream_t stream) {
    const float* x        = (const float*)d_in[0];
    const float* W        = (const float*)d_in[1];
    const float* bias     = (const float*)d_in[2];
    const int*   adj_rows = (const int*)d_in[3];
    const int*   adj_cols = (const int*)d_in[4];
    const float* adj_vals = (const float*)d_in[5];
    float* out = (float*)d_out;
    float* sp  = (float*)d_ws;   // [n_nodes, 64] f32 = 25.6 MB scratch

    const int n_nodes = in_sizes[0] / IN_F;
    const int n_edges = in_sizes[3];

    // 1) sp = x @ W
    gemm_xw<<<(n_nodes + 15) / 16, 256, 0, stream>>>(x, W, sp, n_nodes);

    // 2) out = bias (broadcast)
    const int nvec = n_nodes * (OUT_F / 4);
    init_bias<<<(nvec + 255) / 256, 256, 0, stream>>>(out, bias, n_nodes);

    // 3) out[r] += v * sp[c] over edges
    const long long nthr = (long long)n_edges * 16;
    scatter_edges<<<(int)((nthr + 255) / 256), 256, 0, stream>>>(
        adj_rows, adj_cols, adj_vals, sp, out, n_edges);
}